// Round 7
// baseline (107.142 us; speedup 1.0000x reference)
//
#include <hip/hip_runtime.h>
#include <type_traits>

#define BLOCK 256
#define WAVES_PER_BLOCK 4
#define NBLOCKS 4096
#define TILES_PER_WAVE 8
#define PAIRS (TILES_PER_WAVE/2)

typedef __fp16 f16;
typedef f16 f16x2 __attribute__((ext_vector_type(2)));
typedef f16 f16x8 __attribute__((ext_vector_type(8)));
typedef float f32x16 __attribute__((ext_vector_type(16)));
typedef unsigned u32x2 __attribute__((ext_vector_type(2)));

__device__ __forceinline__ float ex2(float x){ return __builtin_amdgcn_exp2f(x); }
__device__ __forceinline__ float rcp_(float x){ return __builtin_amdgcn_rcpf(x); }
__device__ __forceinline__ float rsq_(float x){ return __builtin_amdgcn_rsqf(x); }

__device__ __forceinline__ unsigned pk2(float a, float b){
    f16x2 h = __builtin_amdgcn_cvt_pkrtz(a, b);
    union { f16x2 h; unsigned u; } cv; cv.h = h; return cv.u;
}

// v_permlane32_swap_b32: r.x[i] = src[i&31] (low-half bcast), r.y[i] = src[32+(i&31)]
__device__ __forceinline__ u32x2 plswap(unsigned a, unsigned b){
    return __builtin_amdgcn_permlane32_swap(a, b, false, false);
}
__device__ __forceinline__ float xhalf_sum(float x){
    union { float f; unsigned u; } cvt; cvt.f = x;
    u32x2 r = plswap(cvt.u, cvt.u);
    union { unsigned u; float f; } lo, hi; lo.u = r.x; hi.u = r.y;
    return lo.f + hi.f;
}
__device__ __forceinline__ float bcast_lo(float x){   // low-half value -> all lanes
    union { float f; unsigned u; } cvt; cvt.f = x;
    u32x2 r = plswap(cvt.u, cvt.u);
    union { unsigned u; float f; } lo; lo.u = r.x;
    return lo.f;
}

// exact-GELU via A&S 7.1.26 erf (|eps| <= 1.5e-7) — table build only
__device__ __forceinline__ float gelu_ref(float v){
    float av = fabsf(v);
    float e  = ex2(v*v * -0.7213475204444817f);
    float t  = rcp_(fmaf(0.23164190157f, av, 1.0f));
    float p  = fmaf(fmaf(fmaf(fmaf(1.061405429f, t, -1.453152027f), t,
                              1.421413741f), t, -0.284496736f), t, 0.254829592f);
    float pt = p * t;
    float erfabs = fmaf(-pt, e, 1.0f);
    return 0.5f * fmaf(av, erfabs, v);
}

union U8 { f16x8 v; unsigned u[4]; };

__global__ __launch_bounds__(BLOCK) void nn_kernel(
    const float* __restrict__ feat,
    const float* __restrict__ W0, const float* __restrict__ b0v,
    const float* __restrict__ g0v, const float* __restrict__ be0v,
    const float* __restrict__ W1, const float* __restrict__ b1v,
    const float* __restrict__ g1v, const float* __restrict__ be1v,
    const float* __restrict__ W2, const float* __restrict__ b2v,
    const float* __restrict__ g2v, const float* __restrict__ be2v,
    const float* __restrict__ Wo, const float* __restrict__ bov,
    float* __restrict__ out)
{
    __shared__ __align__(16) float tabG[4096];   // keep first (offset 0)
    __shared__ __align__(16) float cb[3][16];
    __shared__ __align__(16) float cg[3][16];
    __shared__ __align__(16) float cbe[3][16];
    __shared__ __align__(16) float cbo[4];

    const int tid = threadIdx.x;
    if (tid < 16){
        cb[0][tid]  = b0v[tid];  cb[1][tid]  = b1v[tid];  cb[2][tid]  = b2v[tid];
        cg[0][tid]  = g0v[tid];  cg[1][tid]  = g1v[tid];  cg[2][tid]  = g2v[tid];
        cbe[0][tid] = be0v[tid]; cbe[1][tid] = be1v[tid]; cbe[2][tid] = be2v[tid];
    }
    if (tid < 4) cbo[tid] = bov[tid];
    for (int i = tid; i < 4096; i += BLOCK){
        float v = (float)(i - 2048) * (1.0f/512.0f) + (0.5f/512.0f);
        tabG[i] = gelu_ref(v);
    }
    __syncthreads();

    const int lane = tid & 63;
    const int wv   = tid >> 6;
    const int gg   = lane >> 5;      // k-group / n-group selector
    const int c    = lane & 31;      // A row (neuron n) / B col (data row)

    // ---- weight A-fragments: A[n][k] = W[k][n]; row 16 = column-sums ----
    // (butterfly over lanes 0..31 of each half sums the 16 weight rows; the
    //  c==16 lane keeps the sum -> D[16][m] = sum_n h[m][n] for free)
    U8 aW0, aW1, aW2, aWo;
    auto buildA = [&](const float* W, bool l0) -> U8 {
        float w[8];
        #pragma unroll
        for (int j=0;j<8;++j){
            if (l0){
                if (gg==0) w[j] = (c<16) ? W[j*16 + c] : 0.f;
                else       w[j] = (j==0 && c<16) ? cb[0][c] : 0.f;   // bias col k=8
            } else {
                w[j] = (c<16) ? W[(gg*8+j)*16 + c] : 0.f;
            }
        }
        #pragma unroll
        for (int j=0;j<8;++j){
            float v = w[j];
            v += __shfl_xor(v, 1);  v += __shfl_xor(v, 2);
            v += __shfl_xor(v, 4);  v += __shfl_xor(v, 8);
            v += __shfl_xor(v, 16);
            w[j] = (c==16) ? v : w[j];          // c>16 lanes stay 0
        }
        U8 A;
        A.u[0]=pk2(w[0],w[1]); A.u[1]=pk2(w[2],w[3]);
        A.u[2]=pk2(w[4],w[5]); A.u[3]=pk2(w[6],w[7]);
        return A;
    };
    aW0 = buildA(W0, true);
    aW1 = buildA(W1, false);
    aW2 = buildA(W2, false);
    {
        float w[8];
        #pragma unroll
        for (int j=0;j<8;++j) w[j] = (c<4) ? Wo[(gg*8+j)*4 + c] : 0.f;
        aWo.u[0]=pk2(w[0],w[1]); aWo.u[1]=pk2(w[2],w[3]);
        aWo.u[2]=pk2(w[4],w[5]); aWo.u[3]=pk2(w[6],w[7]);
    }

    // ---- bias sums for layers 1,2 (s-correction), wave-uniform ----
    float Sb1, Sb2;
    {
        float4 a0 = *(const float4*)&cb[1][0], a1 = *(const float4*)&cb[1][4];
        float4 a2 = *(const float4*)&cb[1][8], a3 = *(const float4*)&cb[1][12];
        Sb1 = ((a0.x+a0.y)+(a0.z+a0.w)) + ((a1.x+a1.y)+(a1.z+a1.w))
            + ((a2.x+a2.y)+(a2.z+a2.w)) + ((a3.x+a3.y)+(a3.z+a3.w));
        a0 = *(const float4*)&cb[2][0];  a1 = *(const float4*)&cb[2][4];
        a2 = *(const float4*)&cb[2][8];  a3 = *(const float4*)&cb[2][12];
        Sb2 = ((a0.x+a0.y)+(a0.z+a0.w)) + ((a1.x+a1.y)+(a1.z+a1.w))
            + ((a2.x+a2.y)+(a2.z+a2.w)) + ((a3.x+a3.y)+(a3.z+a3.w));
    }

    // ---- wave-uniform "gamma==1 && beta==0" fast-path flag ----
    bool okl = true;
    if (lane < 16){
        #pragma unroll
        for (int l=0;l<3;++l)
            okl = okl && (cg[l][lane]==1.0f) && (cbe[l][lane]==0.0f);
    }
    const bool triv = (__ballot(okl) == 0xFFFFFFFFFFFFFFFFull);

    // ---- per-lane bias quads for layers 1,2 ----
    const int n0 = 4*gg, n1 = 8 + 4*gg;
    const float4 b1q0 = *(const float4*)&cb[1][n0], b1q1 = *(const float4*)&cb[1][n1];
    const float4 b2q0 = *(const float4*)&cb[2][n0], b2q1 = *(const float4*)&cb[2][n1];
    const float K = 2.8853900817779268f;   // 2/ln2
    const float4 bo2 = make_float4(cbo[0]*K, cbo[1]*K, cbo[2]*K, cbo[3]*K);

    f32x16 zC;
    #pragma unroll
    for (int i=0;i<16;++i) zC[i]=0.f;

    const long gw = (long)blockIdx.x * WAVES_PER_BLOCK + wv;
    const long rowbase = gw * (TILES_PER_WAVE*32L);
    // all-64-lane loads: lane (gg,c) loads row c, half gg of each tile
    const char* fb2 = (const char*)feat + (rowbase + c) * 32L + gg * 16;
    char*       ob  = (char*)out        + (rowbase + c) * 16L;

    auto body = [&](auto TRIVC){
        constexpr bool TRIV = decltype(TRIVC)::value;

        // LN(+gamma/beta) + GELU + pack -> next-layer B fragment
        // e[0..7] already bias-added; sraw = sum of the 16 e-values (from MFMA row16)
        auto lnact = [&](const float* e, float sraw, int l) -> U8 {
            float q0 = fmaf(e[1],e[1], e[0]*e[0]);
            float q1 = fmaf(e[3],e[3], e[2]*e[2]);
            float q2 = fmaf(e[5],e[5], e[4]*e[4]);
            float q3 = fmaf(e[7],e[7], e[6]*e[6]);
            float s2 = (q0+q1) + (q2+q3);
            s2 = xhalf_sum(s2);
            const float mu  = sraw * 0.0625f;
            const float var = fmaxf(fmaf(-mu, mu, s2 * 0.0625f), 0.f);
            const float rs  = rsq_(var + 1e-5f);
            float y[8];
            if constexpr (TRIV){
                const float RSi = rs * 512.f;
                const float NMi = fmaf(-mu, RSi, 2048.f);
                #pragma unroll
                for (int i=0;i<8;++i){
                    float xf = fmaf(e[i], RSi, NMi);
                    xf = fminf(fmaxf(xf, 0.f), 4095.f);      // v_med3
                    y[i] = tabG[(int)xf];
                }
            } else {
                const float nm = -mu * rs;
                const float4 gq0 = *(const float4*)&cg[l][n0];
                const float4 gq1 = *(const float4*)&cg[l][n1];
                const float4 eq0 = *(const float4*)&cbe[l][n0];
                const float4 eq1 = *(const float4*)&cbe[l][n1];
                const float ga[8] = {gq0.x,gq0.y,gq0.z,gq0.w, gq1.x,gq1.y,gq1.z,gq1.w};
                const float ba[8] = {eq0.x,eq0.y,eq0.z,eq0.w, eq1.x,eq1.y,eq1.z,eq1.w};
                #pragma unroll
                for (int i=0;i<8;++i){
                    float t  = fmaf(e[i], rs, nm);
                    t = fmaf(t, ga[i], ba[i]);
                    float xf = fmaf(t, 512.f, 2048.f);
                    xf = fminf(fmaxf(xf, 0.f), 4095.f);
                    y[i] = tabG[(int)xf];
                }
            }
            unsigned P0 = pk2(y[0],y[1]), P1 = pk2(y[2],y[3]);
            unsigned P2 = pk2(y[4],y[5]), P3 = pk2(y[6],y[7]);
            u32x2 e0 = plswap(P0, P2);
            u32x2 e1 = plswap(P1, P3);
            U8 F;
            F.u[0] = e0.x; F.u[1] = e1.x; F.u[2] = e0.y; F.u[3] = e1.y;
            return F;
        };

        // features of pair 0
        float4 pfA = *(const float4*)(fb2 + 0);
        float4 pfB = *(const float4*)(fb2 + 1024);

        #pragma unroll 1
        for (int p = 0; p < PAIRS; ++p){
            // ---- layer-0 B fragments from all-lane loads ----
            // lane(0,c): P0=f01,P1=f23 ; lane(1,c): P0=f45,P1=f67 of row c
            U8 B0, B1;
            {
                unsigned Pa0 = pk2(pfA.x,pfA.y), Pa1 = pk2(pfA.z,pfA.w);
                unsigned Pb0 = pk2(pfB.x,pfB.y), Pb1 = pk2(pfB.z,pfB.w);
                u32x2 ra0 = plswap(Pa0, Pa0), ra1 = plswap(Pa1, Pa1);
                u32x2 rb0 = plswap(Pb0, Pb0), rb1 = plswap(Pb1, Pb1);
                B0.u[0] = gg ? 0x3C00u : Pa0;   // k=8 carries 1.0 (bias col)
                B0.u[1] = gg ? 0u      : Pa1;
                B0.u[2] = gg ? 0u      : ra0.y;
                B0.u[3] = gg ? 0u      : ra1.y;
                B1.u[0] = gg ? 0x3C00u : Pb0;
                B1.u[1] = gg ? 0u      : Pb1;
                B1.u[2] = gg ? 0u      : rb0.y;
                B1.u[3] = gg ? 0u      : rb1.y;
            }

            // ---- prefetch next pair ----
            {
                int pn = (p+1 < PAIRS) ? p+1 : p;
                pfA = *(const float4*)(fb2 + pn*2048L);
                pfB = *(const float4*)(fb2 + pn*2048L + 1024);
            }

            // ---- layer 0 (bias via k-col, mean via row16) ----
            f32x16 h0 = __builtin_amdgcn_mfma_f32_32x32x16_f16(aW0.v, B0.v, zC, 0,0,0);
            f32x16 h1 = __builtin_amdgcn_mfma_f32_32x32x16_f16(aW0.v, B1.v, zC, 0,0,0);

            float e0[8], e1[8];
            #pragma unroll
            for (int i=0;i<8;++i){ e0[i]=h0[i]; e1[i]=h1[i]; }
            U8 F0 = lnact(e0, bcast_lo(h0[8]), 0);
            U8 F1 = lnact(e1, bcast_lo(h1[8]), 0);

            h0 = __builtin_amdgcn_mfma_f32_32x32x16_f16(aW1.v, F0.v, zC, 0,0,0);
            h1 = __builtin_amdgcn_mfma_f32_32x32x16_f16(aW1.v, F1.v, zC, 0,0,0);
            e0[0]=h0[0]+b1q0.x; e0[1]=h0[1]+b1q0.y; e0[2]=h0[2]+b1q0.z; e0[3]=h0[3]+b1q0.w;
            e0[4]=h0[4]+b1q1.x; e0[5]=h0[5]+b1q1.y; e0[6]=h0[6]+b1q1.z; e0[7]=h0[7]+b1q1.w;
            e1[0]=h1[0]+b1q0.x; e1[1]=h1[1]+b1q0.y; e1[2]=h1[2]+b1q0.z; e1[3]=h1[3]+b1q0.w;
            e1[4]=h1[4]+b1q1.x; e1[5]=h1[5]+b1q1.y; e1[6]=h1[6]+b1q1.z; e1[7]=h1[7]+b1q1.w;
            F0 = lnact(e0, bcast_lo(h0[8]) + Sb1, 1);
            F1 = lnact(e1, bcast_lo(h1[8]) + Sb1, 1);

            h0 = __builtin_amdgcn_mfma_f32_32x32x16_f16(aW2.v, F0.v, zC, 0,0,0);
            h1 = __builtin_amdgcn_mfma_f32_32x32x16_f16(aW2.v, F1.v, zC, 0,0,0);
            e0[0]=h0[0]+b2q0.x; e0[1]=h0[1]+b2q0.y; e0[2]=h0[2]+b2q0.z; e0[3]=h0[3]+b2q0.w;
            e0[4]=h0[4]+b2q1.x; e0[5]=h0[5]+b2q1.y; e0[6]=h0[6]+b2q1.z; e0[7]=h0[7]+b2q1.w;
            e1[0]=h1[0]+b2q0.x; e1[1]=h1[1]+b2q0.y; e1[2]=h1[2]+b2q0.z; e1[3]=h1[3]+b2q0.w;
            e1[4]=h1[4]+b2q1.x; e1[5]=h1[5]+b2q1.y; e1[6]=h1[6]+b2q1.z; e1[7]=h1[7]+b2q1.w;
            F0 = lnact(e0, bcast_lo(h0[8]) + Sb2, 2);
            F1 = lnact(e1, bcast_lo(h1[8]) + Sb2, 2);

            h0 = __builtin_amdgcn_mfma_f32_32x32x16_f16(aWo.v, F0.v, zC, 0,0,0);
            h1 = __builtin_amdgcn_mfma_f32_32x32x16_f16(aWo.v, F1.v, zC, 0,0,0);

            // ---- output: f_a = 2 - 2/(exp(z*K + bo*K)+1) ----
            if (gg == 0){
                float4 r0, r1;
                r0.x = fmaf(-2.0f, rcp_(ex2(fmaf(h0[0],K,bo2.x))+1.0f), 2.0f);
                r0.y = fmaf(-2.0f, rcp_(ex2(fmaf(h0[1],K,bo2.y))+1.0f), 2.0f);
                r0.z = fmaf(-2.0f, rcp_(ex2(fmaf(h0[2],K,bo2.z))+1.0f), 2.0f);
                r0.w = fmaf(-2.0f, rcp_(ex2(fmaf(h0[3],K,bo2.w))+1.0f), 2.0f);
                r1.x = fmaf(-2.0f, rcp_(ex2(fmaf(h1[0],K,bo2.x))+1.0f), 2.0f);
                r1.y = fmaf(-2.0f, rcp_(ex2(fmaf(h1[1],K,bo2.y))+1.0f), 2.0f);
                r1.z = fmaf(-2.0f, rcp_(ex2(fmaf(h1[2],K,bo2.z))+1.0f), 2.0f);
                r1.w = fmaf(-2.0f, rcp_(ex2(fmaf(h1[3],K,bo2.w))+1.0f), 2.0f);
                *(float4*)(ob + p*1024L      ) = r0;
                *(float4*)(ob + p*1024L + 512) = r1;
            }
        }
    };

    if (triv) body(std::integral_constant<bool,true>{});
    else      body(std::integral_constant<bool,false>{});
}

extern "C" void kernel_launch(void* const* d_in, const int* in_sizes, int n_in,
                              void* d_out, int out_size, void* d_ws, size_t ws_size,
                              hipStream_t stream) {
    const float* feat = (const float*)d_in[0];
    const float* W0  = (const float*)d_in[1];
    const float* b0  = (const float*)d_in[2];
    const float* g0  = (const float*)d_in[3];
    const float* be0 = (const float*)d_in[4];
    const float* W1  = (const float*)d_in[5];
    const float* b1  = (const float*)d_in[6];
    const float* g1  = (const float*)d_in[7];
    const float* be1 = (const float*)d_in[8];
    const float* W2  = (const float*)d_in[9];
    const float* b2  = (const float*)d_in[10];
    const float* g2  = (const float*)d_in[11];
    const float* be2 = (const float*)d_in[12];
    const float* Wo  = (const float*)d_in[13];
    const float* bo  = (const float*)d_in[14];
    float* out = (float*)d_out;

    hipLaunchKernelGGL(nn_kernel, dim3(NBLOCKS), dim3(BLOCK), 0, stream,
                       feat, W0, b0, g0, be0, W1, b1, g1, be1,
                       W2, b2, g2, be2, Wo, bo, out);
}

// Round 8
// 90.582 us; speedup vs baseline: 1.1828x; 1.1828x over previous
//
#include <hip/hip_runtime.h>
#include <type_traits>

#define BLOCK 256
#define WAVES_PER_BLOCK 4
#define NBLOCKS 4096
#define TILES_PER_WAVE 8
#define QUADS (TILES_PER_WAVE/4)

typedef __fp16 f16;
typedef f16 f16x2 __attribute__((ext_vector_type(2)));
typedef f16 f16x8 __attribute__((ext_vector_type(8)));
typedef float f32x16 __attribute__((ext_vector_type(16)));
typedef unsigned u32x2 __attribute__((ext_vector_type(2)));

__device__ __forceinline__ float ex2(float x){ return __builtin_amdgcn_exp2f(x); }
__device__ __forceinline__ float rcp_(float x){ return __builtin_amdgcn_rcpf(x); }
__device__ __forceinline__ float rsq_(float x){ return __builtin_amdgcn_rsqf(x); }

__device__ __forceinline__ unsigned pk2(float a, float b){
    f16x2 h = __builtin_amdgcn_cvt_pkrtz(a, b);
    union { f16x2 h; unsigned u; } cv; cv.h = h; return cv.u;
}

// v_permlane32_swap_b32: r.x = {a_lo31, b_lo31}, r.y = {a_hi31, b_hi31}
__device__ __forceinline__ u32x2 plswap(unsigned a, unsigned b){
    return __builtin_amdgcn_permlane32_swap(a, b, false, false);
}
__device__ __forceinline__ float xhalf_sum(float x){
    union { float f; unsigned u; } cvt; cvt.f = x;
    u32x2 r = plswap(cvt.u, cvt.u);
    union { unsigned u; float f; } lo, hi; lo.u = r.x; hi.u = r.y;
    return lo.f + hi.f;
}

// exact-GELU via A&S 7.1.26 erf (|eps| <= 1.5e-7) — table build only
__device__ __forceinline__ float gelu_ref(float v){
    float av = fabsf(v);
    float e  = ex2(v*v * -0.7213475204444817f);
    float t  = rcp_(fmaf(0.23164190157f, av, 1.0f));
    float p  = fmaf(fmaf(fmaf(fmaf(1.061405429f, t, -1.453152027f), t,
                              1.421413741f), t, -0.284496736f), t, 0.254829592f);
    float pt = p * t;
    float erfabs = fmaf(-pt, e, 1.0f);
    return 0.5f * fmaf(av, erfabs, v);
}

union U8 { f16x8 v; unsigned u[4]; };

__global__ __launch_bounds__(BLOCK) void nn_kernel(
    const float* __restrict__ feat,
    const float* __restrict__ W0, const float* __restrict__ b0v,
    const float* __restrict__ g0v, const float* __restrict__ be0v,
    const float* __restrict__ W1, const float* __restrict__ b1v,
    const float* __restrict__ g1v, const float* __restrict__ be1v,
    const float* __restrict__ W2, const float* __restrict__ b2v,
    const float* __restrict__ g2v, const float* __restrict__ be2v,
    const float* __restrict__ Wo, const float* __restrict__ bov,
    float* __restrict__ out)
{
    __shared__ __align__(16) float tabG[4096];
    __shared__ __align__(16) float cb[3][16];
    __shared__ __align__(16) float cg[3][16];
    __shared__ __align__(16) float cbe[3][16];
    __shared__ __align__(16) float cbo[4];

    const int tid = threadIdx.x;
    if (tid < 16){
        cb[0][tid]  = b0v[tid];  cb[1][tid]  = b1v[tid];  cb[2][tid]  = b2v[tid];
        cg[0][tid]  = g0v[tid];  cg[1][tid]  = g1v[tid];  cg[2][tid]  = g2v[tid];
        cbe[0][tid] = be0v[tid]; cbe[1][tid] = be1v[tid]; cbe[2][tid] = be2v[tid];
    }
    if (tid < 4) cbo[tid] = bov[tid];
    for (int i = tid; i < 4096; i += BLOCK){
        float v = (float)(i - 2048) * (1.0f/512.0f) + (0.5f/512.0f);
        tabG[i] = gelu_ref(v);
    }
    __syncthreads();

    const int lane = tid & 63;
    const int wv   = tid >> 6;
    const int gg   = lane >> 5;      // k-group / n-group selector
    const int c    = lane & 31;      // A row (neuron) / B col (data row)

    // ---- weight A-fragments: A[n][k] = W[k][n], lane: a[j]=A[c][gg*8+j] ----
    // layer-0: bias folded into k=8 (gg==1, j==0): A[n][8] = b0[n]
    U8 aW0, aW1, aW2, aWo;
    {
        float w[8];
        #pragma unroll
        for (int j=0;j<8;++j){
            if (gg==0) w[j] = (c<16) ? W0[j*16 + c] : 0.f;
            else       w[j] = (j==0 && c<16) ? b0v[c] : 0.f;
        }
        aW0.u[0]=pk2(w[0],w[1]); aW0.u[1]=pk2(w[2],w[3]);
        aW0.u[2]=pk2(w[4],w[5]); aW0.u[3]=pk2(w[6],w[7]);
        #pragma unroll
        for (int j=0;j<8;++j) w[j] = (c<16) ? W1[(gg*8+j)*16 + c] : 0.f;
        aW1.u[0]=pk2(w[0],w[1]); aW1.u[1]=pk2(w[2],w[3]);
        aW1.u[2]=pk2(w[4],w[5]); aW1.u[3]=pk2(w[6],w[7]);
        #pragma unroll
        for (int j=0;j<8;++j) w[j] = (c<16) ? W2[(gg*8+j)*16 + c] : 0.f;
        aW2.u[0]=pk2(w[0],w[1]); aW2.u[1]=pk2(w[2],w[3]);
        aW2.u[2]=pk2(w[4],w[5]); aW2.u[3]=pk2(w[6],w[7]);
        #pragma unroll
        for (int j=0;j<8;++j) w[j] = (c<4) ? Wo[(gg*8+j)*4 + c] : 0.f;
        aWo.u[0]=pk2(w[0],w[1]); aWo.u[1]=pk2(w[2],w[3]);
        aWo.u[2]=pk2(w[4],w[5]); aWo.u[3]=pk2(w[6],w[7]);
    }

    // ---- wave-uniform "gamma==1 && beta==0" fast-path flag ----
    bool okl = true;
    if (lane < 16){
        #pragma unroll
        for (int l=0;l<3;++l)
            okl = okl && (cg[l][lane]==1.0f) && (cbe[l][lane]==0.0f);
    }
    const bool triv = (__ballot(okl) == 0xFFFFFFFFFFFFFFFFull);

    // ---- per-lane bias quads for layers 1,2 ----
    const int n0 = 4*gg, n1 = 8 + 4*gg;
    const float4 b1q0 = *(const float4*)&cb[1][n0], b1q1 = *(const float4*)&cb[1][n1];
    const float4 b2q0 = *(const float4*)&cb[2][n0], b2q1 = *(const float4*)&cb[2][n1];
    const float K = 2.8853900817779268f;   // 2/ln2
    const float4 bo2 = make_float4(cbo[0]*K, cbo[1]*K, cbo[2]*K, cbo[3]*K);

    f32x16 zC;
    #pragma unroll
    for (int i=0;i<16;++i) zC[i]=0.f;

    const long gw = (long)blockIdx.x * WAVES_PER_BLOCK + wv;
    const long rowbase = gw * (TILES_PER_WAVE*32L);
    const char* fb = (const char*)feat + (rowbase + c) * 32L;
    char*       ob = (char*)out        + (rowbase + c) * 16L;

    auto body = [&](auto TRIVC){
        constexpr bool TRIV = decltype(TRIVC)::value;

        // LN + GELU + pack -> next-layer B fragment (R6-verified)
        auto lnact = [&](const float* hv, int l) -> U8 {
            float sa = (hv[0]+hv[1]) + (hv[2]+hv[3]);
            float sb = (hv[4]+hv[5]) + (hv[6]+hv[7]);
            float s  = sa + sb;
            float q0 = fmaf(hv[0],hv[0], hv[1]*hv[1]);
            float q1 = fmaf(hv[2],hv[2], hv[3]*hv[3]);
            float q2 = fmaf(hv[4],hv[4], hv[5]*hv[5]);
            float q3 = fmaf(hv[6],hv[6], hv[7]*hv[7]);
            float s2 = (q0+q1) + (q2+q3);
            s  = xhalf_sum(s);
            s2 = xhalf_sum(s2);
            const float mu  = s * 0.0625f;
            const float var = fmaf(-mu, mu, s2 * 0.0625f);
            const float rs  = rsq_(var + 1e-5f);
            const float nm  = -mu * rs;

            float y[8];
            if constexpr (TRIV){
                #pragma unroll
                for (int i=0;i<8;++i){
                    float t  = fmaf(hv[i], rs, nm);       // |t| <= sqrt(15) < 4
                    y[i] = tabG[(int)fmaf(t, 512.f, 2048.f)];
                }
            } else {
                const float4 gq0 = *(const float4*)&cg[l][n0];
                const float4 gq1 = *(const float4*)&cg[l][n1];
                const float4 eq0 = *(const float4*)&cbe[l][n0];
                const float4 eq1 = *(const float4*)&cbe[l][n1];
                const float ga[8] = {gq0.x,gq0.y,gq0.z,gq0.w, gq1.x,gq1.y,gq1.z,gq1.w};
                const float ba[8] = {eq0.x,eq0.y,eq0.z,eq0.w, eq1.x,eq1.y,eq1.z,eq1.w};
                #pragma unroll
                for (int i=0;i<8;++i){
                    float t  = fmaf(hv[i], rs, nm);
                    t = fmaf(t, ga[i], ba[i]);
                    float xf = fminf(fmaxf(fmaf(t, 512.f, 2048.f), 0.f), 4095.f);
                    y[i] = tabG[(int)xf];
                }
            }
            unsigned P0 = pk2(y[0],y[1]), P1 = pk2(y[2],y[3]);
            unsigned P2 = pk2(y[4],y[5]), P3 = pk2(y[6],y[7]);
            u32x2 e0 = plswap(P0, P2);
            u32x2 e1 = plswap(P1, P3);
            U8 F;
            F.u[0] = e0.x; F.u[1] = e1.x; F.u[2] = e0.y; F.u[3] = e1.y;
            return F;
        };

        #pragma unroll
        for (int q = 0; q < QUADS; ++q){
            const char* fq = fb + q*4096L;

            // ---- issue all 4 tiles' loads back-to-back (gg==0 lanes) ----
            float4 t0a,t0b,t1a,t1b,t2a,t2b,t3a,t3b;
            if (gg==0){
                t0a = *(const float4*)(fq +    0); t0b = *(const float4*)(fq +   16);
                t1a = *(const float4*)(fq + 1024); t1b = *(const float4*)(fq + 1040);
                t2a = *(const float4*)(fq + 2048); t2b = *(const float4*)(fq + 2064);
                t3a = *(const float4*)(fq + 3072); t3b = *(const float4*)(fq + 3088);
            }

            // ---- layer-0 B fragments (k=8 slot = 1.0 bias column) ----
            U8 B0, B1, B2, B3;
            if (gg==0){
                B0.u[0]=pk2(t0a.x,t0a.y); B0.u[1]=pk2(t0a.z,t0a.w);
                B0.u[2]=pk2(t0b.x,t0b.y); B0.u[3]=pk2(t0b.z,t0b.w);
                B1.u[0]=pk2(t1a.x,t1a.y); B1.u[1]=pk2(t1a.z,t1a.w);
                B1.u[2]=pk2(t1b.x,t1b.y); B1.u[3]=pk2(t1b.z,t1b.w);
                B2.u[0]=pk2(t2a.x,t2a.y); B2.u[1]=pk2(t2a.z,t2a.w);
                B2.u[2]=pk2(t2b.x,t2b.y); B2.u[3]=pk2(t2b.z,t2b.w);
                B3.u[0]=pk2(t3a.x,t3a.y); B3.u[1]=pk2(t3a.z,t3a.w);
                B3.u[2]=pk2(t3b.x,t3b.y); B3.u[3]=pk2(t3b.z,t3b.w);
            } else {
                B0.u[0]=0x3C00u; B0.u[1]=0u; B0.u[2]=0u; B0.u[3]=0u;
                B1.u[0]=0x3C00u; B1.u[1]=0u; B1.u[2]=0u; B1.u[3]=0u;
                B2.u[0]=0x3C00u; B2.u[1]=0u; B2.u[2]=0u; B2.u[3]=0u;
                B3.u[0]=0x3C00u; B3.u[1]=0u; B3.u[2]=0u; B3.u[3]=0u;
            }

            // ---- layer 0 ----
            f32x16 h0 = __builtin_amdgcn_mfma_f32_32x32x16_f16(aW0.v, B0.v, zC, 0,0,0);
            f32x16 h1 = __builtin_amdgcn_mfma_f32_32x32x16_f16(aW0.v, B1.v, zC, 0,0,0);
            f32x16 h2 = __builtin_amdgcn_mfma_f32_32x32x16_f16(aW0.v, B2.v, zC, 0,0,0);
            f32x16 h3 = __builtin_amdgcn_mfma_f32_32x32x16_f16(aW0.v, B3.v, zC, 0,0,0);

            float e0[8], e1[8], e2[8], e3[8];
            #pragma unroll
            for (int i=0;i<8;++i){ e0[i]=h0[i]; e1[i]=h1[i]; e2[i]=h2[i]; e3[i]=h3[i]; }
            U8 F0 = lnact(e0, 0);
            U8 F1 = lnact(e1, 0);
            U8 F2 = lnact(e2, 0);
            U8 F3 = lnact(e3, 0);

            // ---- layer 1 ----
            h0 = __builtin_amdgcn_mfma_f32_32x32x16_f16(aW1.v, F0.v, zC, 0,0,0);
            h1 = __builtin_amdgcn_mfma_f32_32x32x16_f16(aW1.v, F1.v, zC, 0,0,0);
            h2 = __builtin_amdgcn_mfma_f32_32x32x16_f16(aW1.v, F2.v, zC, 0,0,0);
            h3 = __builtin_amdgcn_mfma_f32_32x32x16_f16(aW1.v, F3.v, zC, 0,0,0);
            {
                const float ba[8] = {b1q0.x,b1q0.y,b1q0.z,b1q0.w, b1q1.x,b1q1.y,b1q1.z,b1q1.w};
                #pragma unroll
                for (int i=0;i<8;++i){
                    e0[i]=h0[i]+ba[i]; e1[i]=h1[i]+ba[i];
                    e2[i]=h2[i]+ba[i]; e3[i]=h3[i]+ba[i];
                }
            }
            F0 = lnact(e0, 1);
            F1 = lnact(e1, 1);
            F2 = lnact(e2, 1);
            F3 = lnact(e3, 1);

            // ---- layer 2 ----
            h0 = __builtin_amdgcn_mfma_f32_32x32x16_f16(aW2.v, F0.v, zC, 0,0,0);
            h1 = __builtin_amdgcn_mfma_f32_32x32x16_f16(aW2.v, F1.v, zC, 0,0,0);
            h2 = __builtin_amdgcn_mfma_f32_32x32x16_f16(aW2.v, F2.v, zC, 0,0,0);
            h3 = __builtin_amdgcn_mfma_f32_32x32x16_f16(aW2.v, F3.v, zC, 0,0,0);
            {
                const float ba[8] = {b2q0.x,b2q0.y,b2q0.z,b2q0.w, b2q1.x,b2q1.y,b2q1.z,b2q1.w};
                #pragma unroll
                for (int i=0;i<8;++i){
                    e0[i]=h0[i]+ba[i]; e1[i]=h1[i]+ba[i];
                    e2[i]=h2[i]+ba[i]; e3[i]=h3[i]+ba[i];
                }
            }
            F0 = lnact(e0, 2);
            F1 = lnact(e1, 2);
            F2 = lnact(e2, 2);
            F3 = lnact(e3, 2);

            // ---- output layer ----
            h0 = __builtin_amdgcn_mfma_f32_32x32x16_f16(aWo.v, F0.v, zC, 0,0,0);
            h1 = __builtin_amdgcn_mfma_f32_32x32x16_f16(aWo.v, F1.v, zC, 0,0,0);
            h2 = __builtin_amdgcn_mfma_f32_32x32x16_f16(aWo.v, F2.v, zC, 0,0,0);
            h3 = __builtin_amdgcn_mfma_f32_32x32x16_f16(aWo.v, F3.v, zC, 0,0,0);

            // ---- f_a = 2 - 2/(exp(z*K + bo*K)+1) ----
            if (gg == 0){
                float4 r0, r1, r2, r3;
                r0.x = fmaf(-2.0f, rcp_(ex2(fmaf(h0[0],K,bo2.x))+1.0f), 2.0f);
                r0.y = fmaf(-2.0f, rcp_(ex2(fmaf(h0[1],K,bo2.y))+1.0f), 2.0f);
                r0.z = fmaf(-2.0f, rcp_(ex2(fmaf(h0[2],K,bo2.z))+1.0f), 2.0f);
                r0.w = fmaf(-2.0f, rcp_(ex2(fmaf(h0[3],K,bo2.w))+1.0f), 2.0f);
                r1.x = fmaf(-2.0f, rcp_(ex2(fmaf(h1[0],K,bo2.x))+1.0f), 2.0f);
                r1.y = fmaf(-2.0f, rcp_(ex2(fmaf(h1[1],K,bo2.y))+1.0f), 2.0f);
                r1.z = fmaf(-2.0f, rcp_(ex2(fmaf(h1[2],K,bo2.z))+1.0f), 2.0f);
                r1.w = fmaf(-2.0f, rcp_(ex2(fmaf(h1[3],K,bo2.w))+1.0f), 2.0f);
                r2.x = fmaf(-2.0f, rcp_(ex2(fmaf(h2[0],K,bo2.x))+1.0f), 2.0f);
                r2.y = fmaf(-2.0f, rcp_(ex2(fmaf(h2[1],K,bo2.y))+1.0f), 2.0f);
                r2.z = fmaf(-2.0f, rcp_(ex2(fmaf(h2[2],K,bo2.z))+1.0f), 2.0f);
                r2.w = fmaf(-2.0f, rcp_(ex2(fmaf(h2[3],K,bo2.w))+1.0f), 2.0f);
                r3.x = fmaf(-2.0f, rcp_(ex2(fmaf(h3[0],K,bo2.x))+1.0f), 2.0f);
                r3.y = fmaf(-2.0f, rcp_(ex2(fmaf(h3[1],K,bo2.y))+1.0f), 2.0f);
                r3.z = fmaf(-2.0f, rcp_(ex2(fmaf(h3[2],K,bo2.z))+1.0f), 2.0f);
                r3.w = fmaf(-2.0f, rcp_(ex2(fmaf(h3[3],K,bo2.w))+1.0f), 2.0f);
                *(float4*)(ob + q*2048L       ) = r0;
                *(float4*)(ob + q*2048L +  512) = r1;
                *(float4*)(ob + q*2048L + 1024) = r2;
                *(float4*)(ob + q*2048L + 1536) = r3;
            }
        }
    };

    if (triv) body(std::integral_constant<bool,true>{});
    else      body(std::integral_constant<bool,false>{});
}

extern "C" void kernel_launch(void* const* d_in, const int* in_sizes, int n_in,
                              void* d_out, int out_size, void* d_ws, size_t ws_size,
                              hipStream_t stream) {
    const float* feat = (const float*)d_in[0];
    const float* W0  = (const float*)d_in[1];
    const float* b0  = (const float*)d_in[2];
    const float* g0  = (const float*)d_in[3];
    const float* be0 = (const float*)d_in[4];
    const float* W1  = (const float*)d_in[5];
    const float* b1  = (const float*)d_in[6];
    const float* g1  = (const float*)d_in[7];
    const float* be1 = (const float*)d_in[8];
    const float* W2  = (const float*)d_in[9];
    const float* b2  = (const float*)d_in[10];
    const float* g2  = (const float*)d_in[11];
    const float* be2 = (const float*)d_in[12];
    const float* Wo  = (const float*)d_in[13];
    const float* bo  = (const float*)d_in[14];
    float* out = (float*)d_out;

    hipLaunchKernelGGL(nn_kernel, dim3(NBLOCKS), dim3(BLOCK), 0, stream,
                       feat, W0, b0, g0, be0, W1, b1, g1, be1,
                       W2, b2, g2, be2, Wo, bo, out);
}